// Round 4
// baseline (185.193 us; speedup 1.0000x reference)
//
#include <hip/hip_runtime.h>

// Problem shape (fixed by setup_inputs): x = (B=8, H=512, W=512, C=64) fp32, NHWC.
// Outputs: ll, lh, hl, hh each (8, 256, 256, 64) fp32, concatenated in d_out.

#define B_    8
#define H_    512
#define W_    512
#define C_    64
#define HO_   (H_ / 2)
#define WO_   (W_ / 2)
#define CV_   (C_ / 4)                       // float4 chunks per pixel = 16
#define ROWV_ (W_ * CV_)                     // input row stride in float4 = 8192
#define SUBV_ (B_ * HO_ * WO_ * CV_)         // one subband, in float4 = 8388608
#define QUARTV_ (SUBV_ / 4)                  // output chunks per 2 batches
#define INQUART_ (2 * H_ * ROWV_)            // input chunks per 2 batches

typedef float f32x4 __attribute__((ext_vector_type(4)));

__device__ __forceinline__ void haar4(const f32x4 pa, const f32x4 pb,
                                      const f32x4 pc, const f32x4 pd,
                                      f32x4& ll, f32x4& lh, f32x4& hl, f32x4& hh)
{
    const f32x4 sab = pa + pb;
    const f32x4 scd = pc + pd;
    ll = 0.5f * (sab + scd);
    lh = 0.5f * ((pb - pa) + (pd - pc));
    hl = 0.5f * (scd - sab);
    hh = 0.5f * ((pa - pb) + (pd - pc));
}

__global__ __launch_bounds__(256) void WaveLetPooling_38843684225881_kernel(
    const f32x4* __restrict__ x, f32x4* __restrict__ out)
{
    const int idx = blockIdx.x * blockDim.x + threadIdx.x;  // [0, QUARTV_)

    // idx = ((b*HO + h)*WO + w)*CV + cv ; b in [0,2); other 3 positions are
    // the same (h,w,cv) in batches b+2, b+4, b+6 (no extra index decode).
    const int cv = idx & (CV_ - 1);
    const int w  = (idx >> 4) & (WO_ - 1);
    const int h  = (idx >> 12) & (HO_ - 1);
    const int b  = idx >> 20;

    const int in_idx = ((b * H_ + 2 * h) * W_ + 2 * w) * CV_ + cv;

    f32x4 pa[4], pb[4], pc[4], pd[4];
#pragma unroll
    for (int k = 0; k < 4; ++k) {
        const int ii = in_idx + k * INQUART_;
        pa[k] = __builtin_nontemporal_load(&x[ii]);
        pb[k] = __builtin_nontemporal_load(&x[ii + CV_]);
        pc[k] = __builtin_nontemporal_load(&x[ii + ROWV_]);
        pd[k] = __builtin_nontemporal_load(&x[ii + ROWV_ + CV_]);
    }

#pragma unroll
    for (int k = 0; k < 4; ++k) {
        f32x4 ll, lh, hl, hh;
        haar4(pa[k], pb[k], pc[k], pd[k], ll, lh, hl, hh);
        const int oi = idx + k * QUARTV_;
        __builtin_nontemporal_store(ll, &out[oi]);
        __builtin_nontemporal_store(lh, &out[oi + SUBV_]);
        __builtin_nontemporal_store(hl, &out[oi + 2 * SUBV_]);
        __builtin_nontemporal_store(hh, &out[oi + 3 * SUBV_]);
    }
}

extern "C" void kernel_launch(void* const* d_in, const int* in_sizes, int n_in,
                              void* d_out, int out_size, void* d_ws, size_t ws_size,
                              hipStream_t stream) {
    const f32x4* x = (const f32x4*)d_in[0];
    f32x4* out = (f32x4*)d_out;
    const int threads_total = QUARTV_;       // each thread does 4 positions
    const int block = 256;
    const int grid = threads_total / block;  // 8192
    WaveLetPooling_38843684225881_kernel<<<grid, block, 0, stream>>>(x, out);
}